// Round 1
// baseline (379.270 us; speedup 1.0000x reference)
//
#include <hip/hip_runtime.h>
#include <math.h>

#define P_ 32
#define G_ 256
#define NV 6890
#define M_ (2 * NV)          // 13780 joint points per sample
#define NPAIR (P_ * G_)      // 8192

// ---------------- workspace layout ----------------
struct WS {
    float  mu_p[P_][3];        // per-pred centroid
    float  var_p[P_];          // per-pred centered sum of squares
    float  mu_g[G_][3];        // per-gt centroid
    double K[NPAIR][9];        // 3x3 cross-covariance per pair (row=pred coord, col=gt coord)
    float  At[NPAIR][12];      // A = scale*R (9, row-major) then t (3)
    float  pair_err[NPAIR];    // mean v2v error per pair, indexed pair = g*32 + p
};

// ---------------- block reduction (valid on thread 0) ----------------
__device__ inline double block_reduce(double v, double* smem) {
#pragma unroll
    for (int off = 32; off > 0; off >>= 1) v += __shfl_down(v, off, 64);
    int wid  = threadIdx.x >> 6;
    int lane = threadIdx.x & 63;
    __syncthreads();               // protect smem across repeated calls
    if (lane == 0) smem[wid] = v;
    __syncthreads();
    double r = 0.0;
    if (threadIdx.x == 0) {
        int nw = blockDim.x >> 6;
        for (int w = 0; w < nw; ++w) r += smem[w];
    }
    return r;
}

// ---------------- kernel 1: pred stats (mu_p, var_p) ----------------
__global__ __launch_bounds__(256) void pred_stats(const float* __restrict__ pred, WS* ws) {
    int p = blockIdx.x;
    const float* base = pred + (size_t)p * M_ * 3;
    double sx = 0, sy = 0, sz = 0, sq = 0;
    for (int i = threadIdx.x; i < M_; i += 256) {
        float x = base[3 * i + 0];
        float y = base[3 * i + 1];
        float z = base[3 * i + 2];
        sx += x; sy += y; sz += z;
        sq += (double)x * x + (double)y * y + (double)z * z;
    }
    __shared__ double smem[4];
    double rx = block_reduce(sx, smem);
    double ry = block_reduce(sy, smem);
    double rz = block_reduce(sz, smem);
    double rq = block_reduce(sq, smem);
    if (threadIdx.x == 0) {
        double mx = rx / M_, my = ry / M_, mz = rz / M_;
        ws->mu_p[p][0] = (float)mx;
        ws->mu_p[p][1] = (float)my;
        ws->mu_p[p][2] = (float)mz;
        ws->var_p[p] = (float)(rq - (mx * mx + my * my + mz * mz) * (double)M_);
    }
}

// ---------------- kernel 2: gt stats (mu_g) ----------------
__global__ __launch_bounds__(256) void gt_stats(const float* __restrict__ gt, WS* ws) {
    int g = blockIdx.x;
    const float* base = gt + (size_t)g * M_ * 3;
    double sx = 0, sy = 0, sz = 0;
    for (int i = threadIdx.x; i < M_; i += 256) {
        sx += base[3 * i + 0];
        sy += base[3 * i + 1];
        sz += base[3 * i + 2];
    }
    __shared__ double smem[4];
    double rx = block_reduce(sx, smem);
    double ry = block_reduce(sy, smem);
    double rz = block_reduce(sz, smem);
    if (threadIdx.x == 0) {
        ws->mu_g[g][0] = (float)(rx / M_);
        ws->mu_g[g][1] = (float)(ry / M_);
        ws->mu_g[g][2] = (float)(rz / M_);
    }
}

// ---------------- kernel 3: per-pair 3x3 cross-covariance ----------------
// pair = g*32 + p so 32 consecutive blocks share one gt sample (L2 reuse)
__global__ __launch_bounds__(256) void crosscov(const float* __restrict__ pred,
                                                const float* __restrict__ gt, WS* ws) {
    int pair = blockIdx.x;
    int p = pair & 31;
    int g = pair >> 5;
    const float* pb = pred + (size_t)p * M_ * 3;
    const float* gb = gt + (size_t)g * M_ * 3;
    float k[9];
#pragma unroll
    for (int j = 0; j < 9; ++j) k[j] = 0.0f;
    for (int i = threadIdx.x; i < M_; i += 256) {
        float px = pb[3 * i + 0], py = pb[3 * i + 1], pz = pb[3 * i + 2];
        float gx = gb[3 * i + 0], gy = gb[3 * i + 1], gz = gb[3 * i + 2];
        k[0] = fmaf(px, gx, k[0]); k[1] = fmaf(px, gy, k[1]); k[2] = fmaf(px, gz, k[2]);
        k[3] = fmaf(py, gx, k[3]); k[4] = fmaf(py, gy, k[4]); k[5] = fmaf(py, gz, k[5]);
        k[6] = fmaf(pz, gx, k[6]); k[7] = fmaf(pz, gy, k[7]); k[8] = fmaf(pz, gz, k[8]);
    }
    __shared__ double smem[4];
    for (int j = 0; j < 9; ++j) {
        double r = block_reduce((double)k[j], smem);
        if (threadIdx.x == 0) ws->K[pair][j] = r;
    }
    if (threadIdx.x == 0) {
        // subtract M * mu_p mu_g^T
        double mp[3] = { ws->mu_p[p][0], ws->mu_p[p][1], ws->mu_p[p][2] };
        double mg[3] = { ws->mu_g[g][0], ws->mu_g[g][1], ws->mu_g[g][2] };
#pragma unroll
        for (int a = 0; a < 3; ++a)
#pragma unroll
            for (int b = 0; b < 3; ++b)
                ws->K[pair][3 * a + b] -= (double)M_ * mp[a] * mg[b];
    }
}

// ---------------- kernel 4: per-pair SVD -> A = scale*R, t ----------------
__global__ __launch_bounds__(256) void pair_svd(WS* ws) {
    int pair = blockIdx.x * blockDim.x + threadIdx.x;
    if (pair >= NPAIR) return;
    int p = pair & 31;
    int g = pair >> 5;

    double K[3][3];
#pragma unroll
    for (int a = 0; a < 3; ++a)
#pragma unroll
        for (int b = 0; b < 3; ++b) K[a][b] = ws->K[pair][3 * a + b];

    // S = K^T K (symmetric PSD)
    double S[3][3];
#pragma unroll
    for (int a = 0; a < 3; ++a)
#pragma unroll
        for (int b = 0; b < 3; ++b) {
            double acc = 0.0;
#pragma unroll
            for (int c = 0; c < 3; ++c) acc += K[c][a] * K[c][b];
            S[a][b] = acc;
        }

    // Jacobi eigendecomposition S = V Lambda V^T
    double V[3][3] = { {1, 0, 0}, {0, 1, 0}, {0, 0, 1} };
    double tr = S[0][0] + S[1][1] + S[2][2];
    double tol = 1e-30 * tr * tr + 1e-300;
    const int PP[3] = {0, 0, 1};
    const int QQ[3] = {1, 2, 2};
    for (int sweep = 0; sweep < 30; ++sweep) {
        double off = S[0][1] * S[0][1] + S[0][2] * S[0][2] + S[1][2] * S[1][2];
        if (off <= tol) break;
        for (int r3 = 0; r3 < 3; ++r3) {
            int pp = PP[r3], qq = QQ[r3];
            double apq = S[pp][qq];
            if (apq == 0.0) continue;
            double theta = (S[qq][qq] - S[pp][pp]) / (2.0 * apq);
            double t = copysign(1.0, theta) / (fabs(theta) + sqrt(theta * theta + 1.0));
            double c = 1.0 / sqrt(t * t + 1.0);
            double s = t * c;
            // S <- G^T S G (G rotates plane pp,qq)
            for (int r = 0; r < 3; ++r) {           // columns
                double srp = S[r][pp], srq = S[r][qq];
                S[r][pp] = c * srp - s * srq;
                S[r][qq] = s * srp + c * srq;
            }
            for (int cc = 0; cc < 3; ++cc) {        // rows
                double spr = S[pp][cc], sqr = S[qq][cc];
                S[pp][cc] = c * spr - s * sqr;
                S[qq][cc] = s * spr + c * sqr;
            }
            for (int r = 0; r < 3; ++r) {           // accumulate V
                double vrp = V[r][pp], vrq = V[r][qq];
                V[r][pp] = c * vrp - s * vrq;
                V[r][qq] = s * vrp + c * vrq;
            }
        }
    }

    // sort eigenpairs descending
    double lam[3] = { S[0][0], S[1][1], S[2][2] };
    int idx[3] = { 0, 1, 2 };
    if (lam[idx[0]] < lam[idx[1]]) { int t = idx[0]; idx[0] = idx[1]; idx[1] = t; }
    if (lam[idx[0]] < lam[idx[2]]) { int t = idx[0]; idx[0] = idx[2]; idx[2] = t; }
    if (lam[idx[1]] < lam[idx[2]]) { int t = idx[1]; idx[1] = idx[2]; idx[2] = t; }
    double Vs[3][3];
    double sv[3];
#pragma unroll
    for (int i = 0; i < 3; ++i) {
        double l = lam[idx[i]];
        sv[i] = sqrt(l > 0.0 ? l : 0.0);
        for (int r = 0; r < 3; ++r) Vs[r][i] = V[r][idx[i]];
    }

    // U columns: u_i = K v_i / s_i
    double U[3][3];
#pragma unroll
    for (int i = 0; i < 3; ++i) {
        double kx = K[0][0] * Vs[0][i] + K[0][1] * Vs[1][i] + K[0][2] * Vs[2][i];
        double ky = K[1][0] * Vs[0][i] + K[1][1] * Vs[1][i] + K[1][2] * Vs[2][i];
        double kz = K[2][0] * Vs[0][i] + K[2][1] * Vs[1][i] + K[2][2] * Vs[2][i];
        double inv = (sv[i] > 1e-12 * sv[0] && sv[i] > 0.0) ? 1.0 / sv[i] : 0.0;
        U[0][i] = kx * inv; U[1][i] = ky * inv; U[2][i] = kz * inv;
    }
    if (sv[2] <= 1e-12 * sv[0] || sv[0] == 0.0) {
        // rank-deficient fallback: complete with cross product
        U[0][2] = U[1][0] * U[2][1] - U[2][0] * U[1][1];
        U[1][2] = U[2][0] * U[0][1] - U[0][0] * U[2][1];
        U[2][2] = U[0][0] * U[1][1] - U[1][0] * U[0][1];
    }

    double detK = K[0][0] * (K[1][1] * K[2][2] - K[1][2] * K[2][1])
                - K[0][1] * (K[1][0] * K[2][2] - K[1][2] * K[2][0])
                + K[0][2] * (K[1][0] * K[2][1] - K[1][1] * K[2][0]);
    double d = (detK >= 0.0) ? 1.0 : -1.0;

    double varp = (double)ws->var_p[p];
    double scale = (sv[0] + sv[1] + d * sv[2]) / varp;

    // R = Vs * diag(1,1,d) * U^T ; A = scale * R
    float A[9];
#pragma unroll
    for (int a = 0; a < 3; ++a)
#pragma unroll
        for (int b = 0; b < 3; ++b) {
            double r = Vs[a][0] * U[b][0] + Vs[a][1] * U[b][1] + d * Vs[a][2] * U[b][2];
            A[3 * a + b] = (float)(scale * r);
        }
    double mp[3] = { ws->mu_p[p][0], ws->mu_p[p][1], ws->mu_p[p][2] };
    double mg[3] = { ws->mu_g[g][0], ws->mu_g[g][1], ws->mu_g[g][2] };
    float tvec[3];
#pragma unroll
    for (int a = 0; a < 3; ++a)
        tvec[a] = (float)(mg[a] - ((double)A[3 * a + 0] * mp[0] + (double)A[3 * a + 1] * mp[1] +
                                   (double)A[3 * a + 2] * mp[2]));

#pragma unroll
    for (int j = 0; j < 9; ++j) ws->At[pair][j] = A[j];
#pragma unroll
    for (int j = 0; j < 3; ++j) ws->At[pair][9 + j] = tvec[j];
}

// ---------------- kernel 5: per-pair mean v2v error ----------------
__global__ __launch_bounds__(256) void pair_error(const float* __restrict__ pred,
                                                  const float* __restrict__ gt, WS* ws) {
    int pair = blockIdx.x;
    int p = pair & 31;
    int g = pair >> 5;
    const float* pb = pred + (size_t)p * M_ * 3;
    const float* gb = gt + (size_t)g * M_ * 3;
    const float* at = ws->At[pair];
    float a00 = at[0], a01 = at[1], a02 = at[2];
    float a10 = at[3], a11 = at[4], a12 = at[5];
    float a20 = at[6], a21 = at[7], a22 = at[8];
    float t0 = at[9], t1 = at[10], t2 = at[11];

    float acc = 0.0f;
    for (int i = threadIdx.x; i < M_; i += 256) {
        float px = pb[3 * i + 0], py = pb[3 * i + 1], pz = pb[3 * i + 2];
        float gx = gb[3 * i + 0], gy = gb[3 * i + 1], gz = gb[3 * i + 2];
        float vx = fmaf(a00, px, fmaf(a01, py, fmaf(a02, pz, t0))) - gx;
        float vy = fmaf(a10, px, fmaf(a11, py, fmaf(a12, pz, t1))) - gy;
        float vz = fmaf(a20, px, fmaf(a21, py, fmaf(a22, pz, t2))) - gz;
        acc += sqrtf(fmaf(vx, vx, fmaf(vy, vy, vz * vz)));
    }
    __shared__ double smem[4];
    double r = block_reduce((double)acc, smem);
    if (threadIdx.x == 0) ws->pair_err[pair] = (float)(r / (double)M_);
}

// ---------------- kernel 6: argmin over gallery + write outputs ----------------
__global__ void argmin_out(const WS* ws, float* out) {
    int p = threadIdx.x;
    if (p >= P_) return;
    float best = 3.4e38f;
    int bi = 0;
    for (int g = 0; g < G_; ++g) {
        float e = ws->pair_err[g * P_ + p];
        if (e < best) { best = e; bi = g; }
    }
    out[p] = (float)bi;        // mapping
    out[P_ + p] = best;        // min_error
}

extern "C" void kernel_launch(void* const* d_in, const int* in_sizes, int n_in,
                              void* d_out, int out_size, void* d_ws, size_t ws_size,
                              hipStream_t stream) {
    const float* pred = (const float*)d_in[0];   // (32, 2, 6890, 3)
    const float* gt   = (const float*)d_in[1];   // (256, 2, 6890, 3)
    float* out = (float*)d_out;                  // 64 floats: mapping(32) | min_error(32)
    WS* ws = (WS*)d_ws;                          // ~1.0 MB used

    pred_stats<<<dim3(P_), dim3(256), 0, stream>>>(pred, ws);
    gt_stats<<<dim3(G_), dim3(256), 0, stream>>>(gt, ws);
    crosscov<<<dim3(NPAIR), dim3(256), 0, stream>>>(pred, gt, ws);
    pair_svd<<<dim3(NPAIR / 256), dim3(256), 0, stream>>>(ws);
    pair_error<<<dim3(NPAIR), dim3(256), 0, stream>>>(pred, gt, ws);
    argmin_out<<<dim3(1), dim3(64), 0, stream>>>(ws, out);
}